// Round 1
// 1065.075 us; speedup vs baseline: 1.1430x; 1.1430x over previous
//
#include <hip/hip_runtime.h>
#include <hip/hip_bf16.h>

// Problem constants (G=8, H=4096, I=1536, M=16384, m_splits=2048)
#define G_  8
#define H_  4096
#define I_  1536
#define MS_ 2048

typedef float  f32x4  __attribute__((ext_vector_type(4)));
typedef __bf16 bf16x8 __attribute__((ext_vector_type(8)));
typedef unsigned int   u32;
typedef unsigned short u16;

// Async global->LDS, 16B per lane. LDS dest = wave-uniform base + lane*16.
__device__ __forceinline__ void async16(const void* g, void* l) {
    __builtin_amdgcn_global_load_lds(
        (__attribute__((address_space(1))) u32*)g,
        (__attribute__((address_space(3))) u32*)l, 16, 0, 0);
}

// RNE f32 -> bf16 pack of two floats into one u32 (lo = a, hi = b).
__device__ __forceinline__ u32 pack2_bf16(float a, float b) {
    u32 ua = __float_as_uint(a), ub = __float_as_uint(b);
    ua += 0x7fffu + ((ua >> 16) & 1u);
    ub += 0x7fffu + ((ub >> 16) & 1u);
    return (ua >> 16) | (ub & 0xffff0000u);
}

// Pass 1: fp32 -> bf16 bulk convert (8 elems/thread/iter, 16B stores).
__global__ void cvt_bf16(const float* __restrict__ in, u32* __restrict__ out, int n8) {
    int i = blockIdx.x * blockDim.x + threadIdx.x;
    int stride = gridDim.x * blockDim.x;
    for (; i < n8; i += stride) {
        const float4* p = (const float4*)in + (size_t)i * 2;
        float4 a = p[0], b = p[1];
        uint4 r;
        r.x = pack2_bf16(a.x, a.y);
        r.y = pack2_bf16(a.z, a.w);
        r.z = pack2_bf16(b.x, b.y);
        r.w = pack2_bf16(b.z, b.w);
        ((uint4*)out)[i] = r;
    }
}

#define LDS8(p) (*(const bf16x8*)(p))

// ---------------------------------------------------------------------------
// Pass 2: grouped GEMM + fused SwiGLU, 8-phase counted-vmcnt pipeline.
// Block: 512 threads = 8 waves (2 row x 4 col). Tile: 256 rows x (128 gate +
// 128 up) cols, BK=64, double-buffered 128 KiB LDS.
// LDS layout (u16 elems): A0 [0,16384) A1 [16384,32768) B0 [32768,49152)
// B1 [49152,65536); rows are 64 elems (128 B); within each row the eight 16 B
// chunks are XOR-swizzled by (row&7) (T2) -- applied on the global SOURCE for
// global_load_lds (linear dest) and on the ds_read address (same involution).
// Per K-tile, 4 phases: {gate mh0 | up mh0 | gate mh1 | up mh1}, each =
// ds_reads -> barrier -> lgkmcnt(0) -> setprio(1) + 16 MFMA. Staging of tile
// t+2 is distributed over phases 2/3/4 into regions already drained behind a
// barrier. vmcnt(8) at iteration entry keeps next tile's loads in flight.
// ---------------------------------------------------------------------------
template <bool STAGE, bool LAST>
__device__ __forceinline__ void kstep(
    f32x4 (&accg)[8][2], f32x4 (&accu)[8][2],
    const u16* __restrict__ Ar, const u16* __restrict__ Br,
    u16* Aw, u16* Bw,
    const u16*& aS, const u16*& gS, const u16*& uS,
    int la0)
{
    // entry gate: this buffer's 8 loads (issued 2 iterations ago) have landed
    if (LAST) { asm volatile("s_waitcnt vmcnt(0)" ::: "memory"); }
    else      { asm volatile("s_waitcnt vmcnt(8)" ::: "memory"); }
    __builtin_amdgcn_s_barrier();
    __builtin_amdgcn_sched_barrier(0);

    bf16x8 af[4][2], bg[2][2], bu[2][2];

    // ---- phase 1: read A(mh0)+B_gate (12 ds_read_b128); MFMA gate mh0
#pragma unroll
    for (int tt = 0; tt < 4; ++tt) {
        af[tt][0] = LDS8(Ar + tt * 1024 + la0);
        af[tt][1] = LDS8(Ar + tt * 1024 + (la0 ^ 32));
    }
#pragma unroll
    for (int nt = 0; nt < 2; ++nt) {
        bg[nt][0] = LDS8(Br + nt * 1024 + la0);
        bg[nt][1] = LDS8(Br + nt * 1024 + (la0 ^ 32));
    }
    asm volatile("s_waitcnt lgkmcnt(8)" ::: "memory");
    __builtin_amdgcn_s_barrier();
    asm volatile("s_waitcnt lgkmcnt(0)" ::: "memory");
    __builtin_amdgcn_sched_barrier(0);
    __builtin_amdgcn_s_setprio(1);
#pragma unroll
    for (int tt = 0; tt < 4; ++tt)
#pragma unroll
        for (int nt = 0; nt < 2; ++nt)
#pragma unroll
            for (int ks = 0; ks < 2; ++ks)
                accg[tt][nt] = __builtin_amdgcn_mfma_f32_16x16x32_bf16(
                    af[tt][ks], bg[nt][ks], accg[tt][nt], 0, 0, 0);
    __builtin_amdgcn_s_setprio(0);
    __builtin_amdgcn_s_barrier();

    // ---- phase 2: read B_up (4); stage next B_gate (region drained @ph1); MFMA up mh0
#pragma unroll
    for (int nt = 0; nt < 2; ++nt) {
        bu[nt][0] = LDS8(Br + 8192 + nt * 1024 + la0);
        bu[nt][1] = LDS8(Br + 8192 + nt * 1024 + (la0 ^ 32));
    }
    if (STAGE) {
        async16(gS, Bw);
        async16(gS + (size_t)64 * H_, Bw + 4096);
    }
    __builtin_amdgcn_s_barrier();
    asm volatile("s_waitcnt lgkmcnt(0)" ::: "memory");
    __builtin_amdgcn_sched_barrier(0);
    __builtin_amdgcn_s_setprio(1);
#pragma unroll
    for (int tt = 0; tt < 4; ++tt)
#pragma unroll
        for (int nt = 0; nt < 2; ++nt)
#pragma unroll
            for (int ks = 0; ks < 2; ++ks)
                accu[tt][nt] = __builtin_amdgcn_mfma_f32_16x16x32_bf16(
                    af[tt][ks], bu[nt][ks], accu[tt][nt], 0, 0, 0);
    __builtin_amdgcn_s_setprio(0);
    __builtin_amdgcn_s_barrier();

    // ---- phase 3: read A(mh1) (8); stage next B_up (drained @ph2); MFMA gate mh1
#pragma unroll
    for (int tt = 0; tt < 4; ++tt) {
        af[tt][0] = LDS8(Ar + 4096 + tt * 1024 + la0);
        af[tt][1] = LDS8(Ar + 4096 + tt * 1024 + (la0 ^ 32));
    }
    if (STAGE) {
        async16(uS, Bw + 8192);
        async16(uS + (size_t)64 * H_, Bw + 12288);
    }
    __builtin_amdgcn_s_barrier();
    asm volatile("s_waitcnt lgkmcnt(0)" ::: "memory");
    __builtin_amdgcn_sched_barrier(0);
    __builtin_amdgcn_s_setprio(1);
#pragma unroll
    for (int tt = 0; tt < 4; ++tt)
#pragma unroll
        for (int nt = 0; nt < 2; ++nt)
#pragma unroll
            for (int ks = 0; ks < 2; ++ks)
                accg[4 + tt][nt] = __builtin_amdgcn_mfma_f32_16x16x32_bf16(
                    af[tt][ks], bg[nt][ks], accg[4 + tt][nt], 0, 0, 0);
    __builtin_amdgcn_s_setprio(0);
    __builtin_amdgcn_s_barrier();

    // ---- phase 4: stage next A (all A ds_reads drained @ph3); MFMA up mh1 (regs only)
    if (STAGE) {
#pragma unroll
        for (int s = 0; s < 4; ++s)
            async16(aS + (size_t)(s * 64) * H_, Aw + s * 4096);
    }
    __builtin_amdgcn_s_barrier();
    __builtin_amdgcn_s_setprio(1);
#pragma unroll
    for (int tt = 0; tt < 4; ++tt)
#pragma unroll
        for (int nt = 0; nt < 2; ++nt)
#pragma unroll
            for (int ks = 0; ks < 2; ++ks)
                accu[4 + tt][nt] = __builtin_amdgcn_mfma_f32_16x16x32_bf16(
                    af[tt][ks], bu[nt][ks], accu[4 + tt][nt], 0, 0, 0);
    __builtin_amdgcn_s_setprio(0);

    aS += 64; gS += 64; uS += 64;   // advance staging pointers one K-tile
}

__global__ __launch_bounds__(512, 2) void gemm_swiglu8(
    const u16* __restrict__ xbf, const u16* __restrict__ wbf,
    float* __restrict__ out)
{
    __shared__ u16 lds[65536];   // 128 KiB

    // T1: flattened grid, group = blockid&7 -> each XCD owns one group
    const int d  = blockIdx.x;
    const int g  = d & 7;
    const int q  = d >> 3;         // 0..95, ct-fastest (A-panel L2 reuse)
    const int rt = q / 12;
    const int ct = q - rt * 12;
    const int n0 = ct * 128;

    const int tid  = threadIdx.x;
    const int lane = tid & 63;
    const int w    = tid >> 6;
    const int wr   = w >> 2;       // 0..1 wave row
    const int wc   = w & 3;        // 0..3 wave col
    const int fr   = lane & 15;
    const int kq4  = lane >> 4;
    // per-lane ds_read base: row fr, chunk (kq4 ^ (row&7)) -- T2 swizzle
    const int la0  = fr * 64 + ((kq4 ^ (fr & 7)) * 8);
    // staging: thread t covers LDS row t>>3, phys chunk t&7 -> logical chunk
    const int rA   = tid >> 3;                 // 0..63 local row per 8KB step
    const int cA   = (tid & 7) ^ (rA & 7);     // pre-swizzled global chunk

    const u16* xb = xbf + ((size_t)g * MS_ + (size_t)rt * 256) * H_;
    const u16* wb = wbf + (size_t)g * (2 * I_) * H_;

    // wave-local LDS bases
    const u16* A0r = lds + wr * 8192;
    const u16* A1r = A0r + 16384;
    const u16* B0r = lds + 32768 + wc * 2048;
    const u16* B1r = B0r + 16384;
    u16* A0w = lds + w * 512;
    u16* A1w = A0w + 16384;
    u16* B0w = lds + 32768 + w * 512;
    u16* B1w = B0w + 16384;

    f32x4 accg[8][2], accu[8][2];
#pragma unroll
    for (int i = 0; i < 8; ++i)
#pragma unroll
        for (int j = 0; j < 2; ++j) {
            accg[i][j] = f32x4{0.f, 0.f, 0.f, 0.f};
            accu[i][j] = f32x4{0.f, 0.f, 0.f, 0.f};
        }

    const u16* aS = xb + (size_t)rA * H_ + cA * 8;
    const u16* gS = wb + (size_t)(n0 + rA) * H_ + cA * 8;
    const u16* uS = wb + ((size_t)I_ + n0 + rA) * H_ + cA * 8;

    // prologue: stage K-tile 0 -> buf0, K-tile 1 -> buf1 (8 loads each)
#pragma unroll
    for (int s = 0; s < 4; ++s) async16(aS + (size_t)(s * 64) * H_, A0w + s * 4096);
    async16(gS, B0w);              async16(gS + (size_t)64 * H_, B0w + 4096);
    async16(uS, B0w + 8192);       async16(uS + (size_t)64 * H_, B0w + 12288);
#pragma unroll
    for (int s = 0; s < 4; ++s) async16(aS + 64 + (size_t)(s * 64) * H_, A1w + s * 4096);
    async16(gS + 64, B1w);         async16(gS + 64 + (size_t)64 * H_, B1w + 4096);
    async16(uS + 64, B1w + 8192);  async16(uS + 64 + (size_t)64 * H_, B1w + 12288);
    aS += 128; gS += 128; uS += 128;   // -> k-chunk for tile 2

    // main loop: K = 4096 = 64 K-tiles; bodies 0..61 stage tile t+2
#pragma unroll 1
    for (int it = 0; it < 31; ++it) {
        kstep<true, false>(accg, accu, A0r, B0r, A0w, B0w, aS, gS, uS, la0);
        kstep<true, false>(accg, accu, A1r, B1r, A1w, B1w, aS, gS, uS, la0);
    }
    kstep<false, false>(accg, accu, A0r, B0r, A0w, B0w, aS, gS, uS, la0);  // kt=62
    kstep<false, true >(accg, accu, A1r, B1r, A1w, B1w, aS, gS, uS, la0);  // kt=63

    // epilogue: C/D layout col = lane&15, row = (lane>>4)*4 + i  [m89-verified]
    const size_t orow0 = (size_t)g * MS_ + rt * 256 + wr * 128 + (lane >> 4) * 4;
    const int    ocol  = n0 + wc * 32 + fr;
#pragma unroll
    for (int mt = 0; mt < 8; ++mt)
#pragma unroll
        for (int nt = 0; nt < 2; ++nt)
#pragma unroll
            for (int i = 0; i < 4; ++i) {
                float gv = accg[mt][nt][i];
                float uv = accu[mt][nt][i];
                float s  = gv / (1.0f + __expf(-gv));   // silu(gate)
                out[(orow0 + mt * 16 + i) * I_ + (ocol + nt * 16)] = s * uv;
            }
}

// ---------------------------------------------------------------------------
// Fallback (workspace too small): fp32 in-register staging, original structure.
// ---------------------------------------------------------------------------
#define BM 128
#define BN 128
#define BK 32
__global__ __launch_bounds__(256, 2) void gemm_swiglu_fb(
    const float* __restrict__ x, const float* __restrict__ w,
    float* __restrict__ out)
{
    __shared__ __align__(16) u16 As[BM * BK];
    __shared__ __align__(16) u16 Bs[2 * BN * BK];

    const int g    = blockIdx.z;
    const int m0   = blockIdx.y * BM;
    const int n0   = blockIdx.x * BN;
    const int tid  = threadIdx.x;
    const int lane = tid & 63;
    const int wid  = tid >> 6;
    const int wm   = (wid >> 1) * 64;
    const int wn   = (wid & 1) * 64;

    f32x4 accg[4][4], accu[4][4];
#pragma unroll
    for (int i = 0; i < 4; ++i)
#pragma unroll
        for (int j = 0; j < 4; ++j) {
            accg[i][j] = f32x4{0.f, 0.f, 0.f, 0.f};
            accu[i][j] = f32x4{0.f, 0.f, 0.f, 0.f};
        }

    const float* x_b = x + (size_t)(g * MS_ + m0) * H_;
    const float* w_b = w + (size_t)g * (2 * I_) * H_;

    const int fr = lane & 15;
    const int kq = (lane >> 4) * 8;

    for (int k0 = 0; k0 < H_; k0 += BK) {
        const int r  = tid >> 3;
        const int c4 = (tid & 7) * 4;
#pragma unroll
        for (int p = 0; p < 4; ++p) {
            int row  = r + p * 32;
            float4 v = *(const float4*)(x_b + (size_t)row * H_ + k0 + c4);
            uint2 pk;
            pk.x = pack2_bf16(v.x, v.y);
            pk.y = pack2_bf16(v.z, v.w);
            *(uint2*)&As[row * BK + c4] = pk;
        }
#pragma unroll
        for (int p = 0; p < 8; ++p) {
            int row  = r + p * 32;
            int wrow = row < BN ? (n0 + row) : (I_ + n0 + row - BN);
            float4 v = *(const float4*)(w_b + (size_t)wrow * H_ + k0 + c4);
            uint2 pk;
            pk.x = pack2_bf16(v.x, v.y);
            pk.y = pack2_bf16(v.z, v.w);
            *(uint2*)&Bs[row * BK + c4] = pk;
        }
        __syncthreads();

        bf16x8 af[4], bgf[4], buf[4];
#pragma unroll
        for (int t = 0; t < 4; ++t)
            af[t] = *(const bf16x8*)&As[(wm + t * 16 + fr) * BK + kq];
#pragma unroll
        for (int t = 0; t < 4; ++t) {
            bgf[t] = *(const bf16x8*)&Bs[(wn + t * 16 + fr) * BK + kq];
            buf[t] = *(const bf16x8*)&Bs[(BN + wn + t * 16 + fr) * BK + kq];
        }
#pragma unroll
        for (int mt = 0; mt < 4; ++mt)
#pragma unroll
            for (int nt = 0; nt < 4; ++nt) {
                accg[mt][nt] = __builtin_amdgcn_mfma_f32_16x16x32_bf16(
                    af[mt], bgf[nt], accg[mt][nt], 0, 0, 0);
                accu[mt][nt] = __builtin_amdgcn_mfma_f32_16x16x32_bf16(
                    af[mt], buf[nt], accu[mt][nt], 0, 0, 0);
            }
        __syncthreads();
    }

    const int orow_b = g * MS_ + m0 + wm + (lane >> 4) * 4;
    const int ocol_b = n0 + wn + fr;
#pragma unroll
    for (int mt = 0; mt < 4; ++mt)
#pragma unroll
        for (int nt = 0; nt < 4; ++nt)
#pragma unroll
            for (int i = 0; i < 4; ++i) {
                float gv = accg[mt][nt][i];
                float uv = accu[mt][nt][i];
                float s  = gv / (1.0f + __expf(-gv));
                out[(size_t)(orow_b + mt * 16 + i) * I_ + (ocol_b + nt * 16)] = s * uv;
            }
}

extern "C" void kernel_launch(void* const* d_in, const int* in_sizes, int n_in,
                              void* d_out, int out_size, void* d_ws, size_t ws_size,
                              hipStream_t stream) {
    const float* x = (const float*)d_in[0];
    const float* w = (const float*)d_in[1];
    float* out = (float*)d_out;

    const size_t xe = (size_t)G_ * MS_ * H_;        //  67,108,864 elems
    const size_t we = (size_t)G_ * 2 * I_ * H_;     // 100,663,296 elems
    const size_t need = (xe + we) * sizeof(u16);    // 320 MiB

    if (ws_size >= need) {
        u16* xbf = (u16*)d_ws;
        u16* wbf = xbf + xe;
        cvt_bf16<<<4096, 256, 0, stream>>>(x, (u32*)xbf, (int)(xe / 8));
        cvt_bf16<<<4096, 256, 0, stream>>>(w, (u32*)wbf, (int)(we / 8));
        gemm_swiglu8<<<dim3(768), dim3(512), 0, stream>>>(xbf, wbf, out);
    } else {
        gemm_swiglu_fb<<<dim3(I_ / BN, MS_ / BM, G_), dim3(256), 0, stream>>>(x, w, out);
    }
}